// Round 1
// baseline (25117.508 us; speedup 1.0000x reference)
//
#include <hip/hip_runtime.h>

// Problem constants (from reference)
#define BB    2048
#define TT    100
#define CC    8
#define HD    64
#define HHD   128
#define OO    10
#define MROWS 4      // batch rows per block; grid = 512 blocks = 2 blocks/CU
#define NTHR  512    // 8 waves/block; __launch_bounds__(NTHR,4) caps VGPR at 128
                     // so TWO blocks co-reside per CU (16 waves/CU, was 8)

__device__ __forceinline__ float fast_tanh(float x) {
  float e = __expf(2.0f * x);
  return 1.0f - 2.0f / (e + 1.0f);
}

__global__ void zero_out_k(float* o) {
  if (threadIdx.x < 2) o[threadIdx.x] = 0.0f;
}

// Hidden layer slice: all MROWS rows, k in [kb,kb+16), lane cols (l, l+64).
// Each weight row is loaded exactly once per block per stage (8 waves x 16 k
// covers all 128 k). Weights streamed from global (L2-hot); relu on read.
// Live regs ~60: wx/wy 32 + hk 16 + acc 8 + addressing.
__device__ __forceinline__ void hidden_layer(const float* __restrict__ Wg,
                                             const float (*pin)[HHD],
                                             float (*pout)[HHD],
                                             int l, int kb) {
  float wx[16], wy[16];
#pragma unroll
  for (int j = 0; j < 16; ++j) {
    const float* wr = Wg + (kb + j) * HHD;
    wx[j] = wr[l];                            // 256B coalesced per wave
    wy[j] = wr[l + 64];
  }
  float a0[MROWS], a1[MROWS];
#pragma unroll
  for (int rr = 0; rr < MROWS; ++rr) { a0[rr] = 0.f; a1[rr] = 0.f; }
#pragma unroll
  for (int rr = 0; rr < MROWS; ++rr) {
    const float* pr = &pin[rr][kb];
    const float4 h0 = *(const float4*)(pr);       // wave-uniform -> broadcast
    const float4 h1 = *(const float4*)(pr + 4);
    const float4 h2 = *(const float4*)(pr + 8);
    const float4 h3 = *(const float4*)(pr + 12);
    const float hk[16] = {
      fmaxf(h0.x,0.f), fmaxf(h0.y,0.f), fmaxf(h0.z,0.f), fmaxf(h0.w,0.f),
      fmaxf(h1.x,0.f), fmaxf(h1.y,0.f), fmaxf(h1.z,0.f), fmaxf(h1.w,0.f),
      fmaxf(h2.x,0.f), fmaxf(h2.y,0.f), fmaxf(h2.z,0.f), fmaxf(h2.w,0.f),
      fmaxf(h3.x,0.f), fmaxf(h3.y,0.f), fmaxf(h3.z,0.f), fmaxf(h3.w,0.f) };
#pragma unroll
    for (int k = 0; k < 16; ++k) {
      a0[rr] = fmaf(hk[k], wx[k], a0[rr]);
      a1[rr] = fmaf(hk[k], wy[k], a1[rr]);
    }
  }
#pragma unroll
  for (int rr = 0; rr < MROWS; ++rr) {          // ds_add_f32, 2 lanes/bank = free
    atomicAdd(&pout[rr][l],      a0[rr]);
    atomicAdd(&pout[rr][l + 64], a1[rr]);
  }
}

__global__ void __launch_bounds__(NTHR, 4)
cde_main(const float* __restrict__ coeffs, const int* __restrict__ yy,
         const float* __restrict__ times,
         const float* __restrict__ W_init, const float* __restrict__ b_init,
         const float* __restrict__ W_in,  const float* __restrict__ b_in,
         const float* __restrict__ W_h,   const float* __restrict__ b_h,
         const float* __restrict__ W_out, const float* __restrict__ b_out,
         const float* __restrict__ W_read,const float* __restrict__ b_read,
         float* __restrict__ out)
{
  __shared__ float sZs[MROWS][HD];        // 1KB   stage-input z
  __shared__ float pA [MROWS][HHD];       // 2KB   bias-primed partials, layer A
  __shared__ float p1 [MROWS][HHD];       // 2KB   hidden1
  __shared__ float p2 [MROWS][HHD];       // 2KB   hidden2
  __shared__ float pB [MROWS][576];       // 9KB   big layer, addr = col + (col>>3)
  __shared__ float sDx[MROWS][CC];
  __shared__ float sLog[MROWS][OO];
  // total ~16.4KB -> 2 blocks/CU is LDS-trivial; limit is the 128-VGPR cap

  const int t    = threadIdx.x;
  const int wv   = t >> 6;        // wave id 0..7
  const int l    = t & 63;        // lane
  const int row0 = blockIdx.x * MROWS;
  // P4 mapping: k-slice q = wv&3 (32k), col-half = wv>>2 (256 cols, 4/lane)
  const int q    = wv & 3;
  const int colb = 256 * (wv >> 2) + 4 * l;

  // tiny persistent scalars only (~20 regs incl addressing)
  const float binx = b_in[l],      biny = b_in[l + 64];
  const float b1x  = b_h[l],       b1y  = b_h[l + 64];
  const float b2x  = b_h[HHD + l], b2y  = b_h[HHD + l + 64];
  const float boutv = b_out[t];

  // ---- z0 ; thread owns (row wv, h=l) for RK state (waves 0..3 only) ----
  float z0 = 0.f, kacc = 0.f;
  if (wv < MROWS) {
    const float* cf = coeffs + (size_t)(row0 + wv) * (TT*CC);
    float a = b_init[l];
#pragma unroll
    for (int c = 0; c < CC; ++c) a = fmaf(cf[c], W_init[c*HD + l], a);
    z0 = a;
    sZs[wv][l] = a;
    // ---- prime partial buffers with bias ----
    pA[wv][l] = binx;  pA[wv][l + 64] = biny;
    p1[wv][l] = b1x;   p1[wv][l + 64] = b1y;
    p2[wv][l] = b2x;   p2[wv][l + 64] = b2y;
  }
#pragma unroll
  for (int r = 0; r < MROWS; ++r) pB[r][t + (t >> 3)] = boutv;
  __syncthreads();

#pragma unroll 1
  for (int step = 0; step < TT-1; ++step) {
    const float dti = times[step+1] - times[step];
    if (t < MROWS * CC) {   // sDx readers (P5) are barrier-separated both ways
      const int r = t >> 3, c = t & 7;
      const float* cf = coeffs + (size_t)(row0 + r)*(TT*CC) + step*CC + c;
      sDx[r][c] = (cf[CC] - cf[0]) / dti;
    }

#pragma unroll 1
    for (int s = 0; s < 4; ++s) {
      // ---- P1: layer A. all rows, k in [8wv, 8wv+8). + prime pB ----
      {
        const int kb = 8 * wv;
        float wx[8], wy[8];
#pragma unroll
        for (int j = 0; j < 8; ++j) {
          const float* wr = W_in + (kb + j) * HHD;
          wx[j] = wr[l];
          wy[j] = wr[l + 64];
        }
#pragma unroll
        for (int rr = 0; rr < MROWS; ++rr) {
          const float* zr = &sZs[rr][kb];
          const float4 za = *(const float4*)(zr);
          const float4 zb = *(const float4*)(zr + 4);
          const float zk[8] = {za.x, za.y, za.z, za.w, zb.x, zb.y, zb.z, zb.w};
          float a0 = 0.f, a1 = 0.f;
#pragma unroll
          for (int k = 0; k < 8; ++k) {
            a0 = fmaf(zk[k], wx[k], a0);
            a1 = fmaf(zk[k], wy[k], a1);
          }
          atomicAdd(&pA[rr][l],      a0);
          atomicAdd(&pA[rr][l + 64], a1);
        }
#pragma unroll
        for (int r = 0; r < MROWS; ++r) pB[r][t + (t >> 3)] = boutv;
      }
      __syncthreads();
      // ---- P2: hidden1 (reads pA, relu inline). k in [16wv,16wv+16) ----
      hidden_layer(W_h, pA, p1, l, 16 * wv);
      __syncthreads();
      // ---- P3: hidden2 (reads p1) + rebias pA ----
      hidden_layer(W_h + HHD*HHD, p1, p2, l, 16 * wv);
      if (wv < MROWS) { pA[wv][l] = binx;  pA[wv][l + 64] = biny; }
      __syncthreads();
      // ---- P4: big layer. k in [32q,32q+32), cols colb..colb+3. + rebias p1 ----
      {
        float acc[MROWS][4];
#pragma unroll
        for (int r = 0; r < MROWS; ++r)
#pragma unroll
          for (int c = 0; c < 4; ++c) acc[r][c] = 0.f;

        const float* wp = W_out + (size_t)(32*q) * (HD*CC) + colb;
#pragma unroll
        for (int kc = 0; kc < 8; ++kc) {
          float4 w4[4];                         // 16 regs, chunk-local
#pragma unroll
          for (int j = 0; j < 4; ++j)
            w4[j] = *(const float4*)(wp + (4*kc + j)*(HD*CC));   // 1KB/wave coalesced
          const int k0 = 32*q + 4*kc;
#pragma unroll
          for (int r = 0; r < MROWS; ++r) {
            const float4 hv = *(const float4*)&p2[r][k0];        // broadcast
            const float hf[4] = { fmaxf(hv.x,0.f), fmaxf(hv.y,0.f),
                                  fmaxf(hv.z,0.f), fmaxf(hv.w,0.f) };
#pragma unroll
            for (int j = 0; j < 4; ++j) {
              acc[r][0] = fmaf(hf[j], w4[j].x, acc[r][0]);
              acc[r][1] = fmaf(hf[j], w4[j].y, acc[r][1]);
              acc[r][2] = fmaf(hf[j], w4[j].z, acc[r][2]);
              acc[r][3] = fmaf(hf[j], w4[j].w, acc[r][3]);
            }
          }
        }
#pragma unroll
        for (int r = 0; r < MROWS; ++r)
#pragma unroll
          for (int c = 0; c < 4; ++c) {
            const int col = colb + c;
            atomicAdd(&pB[r][col + (col >> 3)], acc[r][c]);
          }
        if (wv < MROWS) { p1[wv][l] = b1x;  p1[wv][l + 64] = b1y; }
      }
      __syncthreads();
      // ---- P5: epilogue (tanh, einsum dX, RK) + rebias p2 (waves 0..3) ----
      if (wv < MROWS) {
        const float* pr = &pB[wv][9*l];       // cols 8l..8l+7, stride-9 conflict-free
        const float u0 = pr[0], u1 = pr[1], u2 = pr[2], u3 = pr[3];
        const float u4 = pr[4], u5 = pr[5], u6 = pr[6], u7 = pr[7];
        const float4 d0 = *(const float4*)&sDx[wv][0];   // broadcast
        const float4 d1 = *(const float4*)&sDx[wv][4];
        float g = fast_tanh(u0)*d0.x + fast_tanh(u1)*d0.y
                + fast_tanh(u2)*d0.z + fast_tanh(u3)*d0.w
                + fast_tanh(u4)*d1.x + fast_tanh(u5)*d1.y
                + fast_tanh(u6)*d1.z + fast_tanh(u7)*d1.w;
        if (s == 0)      kacc = g;
        else if (s == 3) kacc += g;
        else             kacc += 2.0f * g;
        float zs;
        if (s == 3) {
          z0 = z0 + dti * (1.0f/6.0f) * kacc;
          zs = z0;
        } else {
          zs = z0 + ((s == 2) ? dti : 0.5f * dti) * g;
        }
        sZs[wv][l] = zs;
        p2[wv][l] = b2x;  p2[wv][l + 64] = b2y;
      }
      __syncthreads();
    } // stages
  }   // steps

  // ---- readout: logits = zT @ W_read + b_read ; loss + accuracy ----
  if (t < MROWS * OO) {
    const int r = t / OO, o = t % OO;
    float a = b_read[o];
#pragma unroll 8
    for (int k = 0; k < HD; ++k) a = fmaf(sZs[r][k], W_read[k*OO + o], a);
    sLog[r][o] = a;
  }
  __syncthreads();
  if (t < 64) {
    float lv = 0.f, cv = 0.f;
    if (t < MROWS) {
      const int r = t;
      float mx = sLog[r][0]; int am = 0;
#pragma unroll
      for (int o = 1; o < OO; ++o) { const float v = sLog[r][o]; if (v > mx) { mx = v; am = o; } }
      float se = 0.f;
#pragma unroll
      for (int o = 0; o < OO; ++o) se += expf(sLog[r][o] - mx);
      const float lse = mx + logf(se);
      const int yr = yy[row0 + r];
      lv = (lse - sLog[r][yr]) * (1.0f / (float)BB);
      cv = (am == yr) ? 1.0f : 0.0f;
    }
    lv += __shfl_xor(lv, 1); lv += __shfl_xor(lv, 2);
    cv += __shfl_xor(cv, 1); cv += __shfl_xor(cv, 2);
    if (t == 0) { atomicAdd(&out[0], lv); atomicAdd(&out[1], cv); }
  }
}

extern "C" void kernel_launch(void* const* d_in, const int* in_sizes, int n_in,
                              void* d_out, int out_size, void* d_ws, size_t ws_size,
                              hipStream_t stream) {
  const float* coeffs = (const float*)d_in[0];
  const int*   y      = (const int*)  d_in[1];
  const float* times  = (const float*)d_in[2];
  const float* W_init = (const float*)d_in[3];
  const float* b_init = (const float*)d_in[4];
  const float* W_in   = (const float*)d_in[5];
  const float* b_in   = (const float*)d_in[6];
  const float* W_h    = (const float*)d_in[7];
  const float* b_h    = (const float*)d_in[8];
  const float* W_out  = (const float*)d_in[9];
  const float* b_out  = (const float*)d_in[10];
  const float* W_read = (const float*)d_in[11];
  const float* b_read = (const float*)d_in[12];
  float* out = (float*)d_out;

  zero_out_k<<<1, 64, 0, stream>>>(out);   // d_out is poisoned 0xAA before every replay
  cde_main<<<BB/MROWS, NTHR, 0, stream>>>(coeffs, y, times, W_init, b_init,
                                          W_in, b_in, W_h, b_h, W_out, b_out,
                                          W_read, b_read, out);
}

// Round 3
// 22487.488 us; speedup vs baseline: 1.1170x; 1.1170x over previous
//
#include <hip/hip_runtime.h>

// Problem constants (from reference)
#define BB    2048
#define TT    100
#define CC    8
#define HD    64
#define HHD   128
#define OO    10
#define MROWS 8      // batch rows per block; grid = 256 blocks = 1 block/CU
#define NTHR  512    // 8 waves/block = 2 waves/SIMD; launch_bounds(512,2) -> 256 VGPR cap
// Round-1 lesson: 2 blocks/CU with MROWS=4 DOUBLED the weight refetch (FETCH
// 1.2e7->3.1e7 KB) and regressed 35%. Kernel is weight-refetch latency-bound.
// This version register-caches W_h (64 regs/thread) + W_out (128 regs/thread)
// across the whole time loop; only W_in (32KB, L2-hot) is still streamed.
// Round-2 was an infra failure (container died twice, no counters) — this is
// the same experiment resubmitted.

__device__ __forceinline__ float fast_tanh(float x) {
  float e = __expf(2.0f * x);
  return 1.0f - 2.0f / (e + 1.0f);
}

__global__ void zero_out_k(float* o) {
  if (threadIdx.x < 2) o[threadIdx.x] = 0.0f;
}

// Hidden layer slice with REGISTER-cached weights: all MROWS rows,
// k in [kb,kb+16), lane cols (l, l+64). Per-row processing keeps live
// regs low: 16 hk + 2 acc on top of persistent weights.
__device__ __forceinline__ void hidden_cached(const float* __restrict__ wx,
                                              const float* __restrict__ wy,
                                              const float (*pin)[HHD],
                                              float (*pout)[HHD],
                                              int l, int kb) {
#pragma unroll
  for (int rr = 0; rr < MROWS; ++rr) {
    const float* pr = &pin[rr][kb];
    const float4 h0 = *(const float4*)(pr);       // wave-uniform -> broadcast
    const float4 h1 = *(const float4*)(pr + 4);
    const float4 h2 = *(const float4*)(pr + 8);
    const float4 h3 = *(const float4*)(pr + 12);
    const float hk[16] = {
      fmaxf(h0.x,0.f), fmaxf(h0.y,0.f), fmaxf(h0.z,0.f), fmaxf(h0.w,0.f),
      fmaxf(h1.x,0.f), fmaxf(h1.y,0.f), fmaxf(h1.z,0.f), fmaxf(h1.w,0.f),
      fmaxf(h2.x,0.f), fmaxf(h2.y,0.f), fmaxf(h2.z,0.f), fmaxf(h2.w,0.f),
      fmaxf(h3.x,0.f), fmaxf(h3.y,0.f), fmaxf(h3.z,0.f), fmaxf(h3.w,0.f) };
    float a0 = 0.f, a1 = 0.f;
#pragma unroll
    for (int k = 0; k < 16; ++k) {
      a0 = fmaf(hk[k], wx[k], a0);
      a1 = fmaf(hk[k], wy[k], a1);
    }
    atomicAdd(&pout[rr][l],      a0);   // ds_add_f32, 2 lanes/bank = free
    atomicAdd(&pout[rr][l + 64], a1);
  }
}

__global__ void __launch_bounds__(NTHR, 2)
cde_main(const float* __restrict__ coeffs, const int* __restrict__ yy,
         const float* __restrict__ times,
         const float* __restrict__ W_init, const float* __restrict__ b_init,
         const float* __restrict__ W_in,  const float* __restrict__ b_in,
         const float* __restrict__ W_h,   const float* __restrict__ b_h,
         const float* __restrict__ W_out, const float* __restrict__ b_out,
         const float* __restrict__ W_read,const float* __restrict__ b_read,
         float* __restrict__ out)
{
  __shared__ float sZs[MROWS][HD];        // 2KB   stage-input z
  __shared__ float pA [MROWS][HHD];       // 4KB   bias-primed partials, layer A
  __shared__ float p1 [MROWS][HHD];       // 4KB   hidden1
  __shared__ float p2 [MROWS][HHD];       // 4KB   hidden2
  __shared__ float pB [MROWS][576];       // 18KB  big layer, addr = col + (col>>3)
  __shared__ float sDx[MROWS][CC];
  __shared__ float sLog[MROWS][OO];

  const int t    = threadIdx.x;
  const int wv   = t >> 6;        // wave id 0..7
  const int l    = t & 63;        // lane
  const int row0 = blockIdx.x * MROWS;
  // P4 mapping: k-slice q = wv&3 (32k), col-half = wv>>2 (256 cols, 4/lane)
  const int q    = wv & 3;
  const int colb = 256 * (wv >> 2) + 4 * l;

  // ---- persistent register-cached weights (loaded ONCE) ----
  // W_h layers: wave wv owns k-rows [16wv,16wv+16), cols l and l+64. 64 regs.
  float w1x[16], w1y[16], w2x[16], w2y[16];
#pragma unroll
  for (int j = 0; j < 16; ++j) {
    const float* wr  = W_h + (16*wv + j) * HHD;           // 256B coalesced
    const float* wr2 = wr + HHD*HHD;
    w1x[j] = wr[l];   w1y[j] = wr[l + 64];
    w2x[j] = wr2[l];  w2y[j] = wr2[l + 64];
  }
  // W_out: thread owns rows 32q+4kc+j, cols colb..colb+3. 128 regs.
  float4 wout[8][4];
#pragma unroll
  for (int kc = 0; kc < 8; ++kc)
#pragma unroll
    for (int j = 0; j < 4; ++j)
      wout[kc][j] = *(const float4*)(W_out + (size_t)(32*q + 4*kc + j)*(HD*CC) + colb);

  // biases (7 regs)
  const float binx = b_in[l],      biny = b_in[l + 64];
  const float b1x  = b_h[l],       b1y  = b_h[l + 64];
  const float b2x  = b_h[HHD + l], b2y  = b_h[HHD + l + 64];
  const float boutv = b_out[t];

  // ---- z0 ; thread owns (row wv, h=l) for RK state ----
  float z0, kacc = 0.f;
  {
    const float* cf = coeffs + (size_t)(row0 + wv) * (TT*CC);
    float a = b_init[l];
#pragma unroll
    for (int c = 0; c < CC; ++c) a = fmaf(cf[c], W_init[c*HD + l], a);
    z0 = a;
    sZs[wv][l] = a;
  }

  // ---- prime partial buffers with bias ----
  pA[wv][l] = binx;  pA[wv][l + 64] = biny;
  p1[wv][l] = b1x;   p1[wv][l + 64] = b1y;
  p2[wv][l] = b2x;   p2[wv][l + 64] = b2y;
#pragma unroll
  for (int r = 0; r < MROWS; ++r) pB[r][t + (t >> 3)] = boutv;
  __syncthreads();

#pragma unroll 1
  for (int step = 0; step < TT-1; ++step) {
    const float dti = times[step+1] - times[step];
    if (t < 64) {   // sDx readers (P5) are barrier-separated both directions
      const int r = t >> 3, c = t & 7;
      const float* cf = coeffs + (size_t)(row0 + r)*(TT*CC) + step*CC + c;
      sDx[r][c] = (cf[CC] - cf[0]) / dti;
    }

#pragma unroll 1
    for (int s = 0; s < 4; ++s) {
      // ---- P1: layer A. all rows, k in [8wv,8wv+8). W_in streamed (L2-hot).
      //      + prime pB ----
      {
        const int kb = 8 * wv;
        float wx[8], wy[8];
#pragma unroll
        for (int j = 0; j < 8; ++j) {
          const float* wr = W_in + (kb + j) * HHD;
          wx[j] = wr[l];
          wy[j] = wr[l + 64];
        }
#pragma unroll
        for (int rr = 0; rr < MROWS; ++rr) {
          const float* zr = &sZs[rr][kb];
          const float4 za = *(const float4*)(zr);
          const float4 zb = *(const float4*)(zr + 4);
          const float zk[8] = {za.x, za.y, za.z, za.w, zb.x, zb.y, zb.z, zb.w};
          float a0 = 0.f, a1 = 0.f;
#pragma unroll
          for (int k = 0; k < 8; ++k) {
            a0 = fmaf(zk[k], wx[k], a0);
            a1 = fmaf(zk[k], wy[k], a1);
          }
          atomicAdd(&pA[rr][l],      a0);
          atomicAdd(&pA[rr][l + 64], a1);
        }
#pragma unroll
        for (int r = 0; r < MROWS; ++r) pB[r][t + (t >> 3)] = boutv;
      }
      __syncthreads();
      // ---- P2: hidden1 (reads pA, relu inline), cached weights ----
      hidden_cached(w1x, w1y, pA, p1, l, 16 * wv);
      __syncthreads();
      // ---- P3: hidden2 (reads p1), cached weights + rebias pA ----
      hidden_cached(w2x, w2y, p1, p2, l, 16 * wv);
      pA[wv][l] = binx;  pA[wv][l + 64] = biny;
      __syncthreads();
      // ---- P4: big layer, fully register-cached W_out.
      //      k in [32q,32q+32), cols colb..colb+3. + rebias p1 ----
      {
#pragma unroll
        for (int r = 0; r < MROWS; ++r) {
          float ac0 = 0.f, ac1 = 0.f, ac2 = 0.f, ac3 = 0.f;
#pragma unroll
          for (int kc = 0; kc < 8; ++kc) {
            const float4 hv = *(const float4*)&p2[r][32*q + 4*kc];   // broadcast
            const float hf[4] = { fmaxf(hv.x,0.f), fmaxf(hv.y,0.f),
                                  fmaxf(hv.z,0.f), fmaxf(hv.w,0.f) };
#pragma unroll
            for (int j = 0; j < 4; ++j) {
              ac0 = fmaf(hf[j], wout[kc][j].x, ac0);
              ac1 = fmaf(hf[j], wout[kc][j].y, ac1);
              ac2 = fmaf(hf[j], wout[kc][j].z, ac2);
              ac3 = fmaf(hf[j], wout[kc][j].w, ac3);
            }
          }
          atomicAdd(&pB[r][(colb    ) + ((colb    ) >> 3)], ac0);
          atomicAdd(&pB[r][(colb + 1) + ((colb + 1) >> 3)], ac1);
          atomicAdd(&pB[r][(colb + 2) + ((colb + 2) >> 3)], ac2);
          atomicAdd(&pB[r][(colb + 3) + ((colb + 3) >> 3)], ac3);
        }
        p1[wv][l] = b1x;  p1[wv][l + 64] = b1y;
      }
      __syncthreads();
      // ---- P5: epilogue (tanh, einsum dX, RK) + rebias p2 ----
      {
        const float* pr = &pB[wv][9*l];       // cols 8l..8l+7, stride-9 conflict-free
        const float u0 = pr[0], u1 = pr[1], u2 = pr[2], u3 = pr[3];
        const float u4 = pr[4], u5 = pr[5], u6 = pr[6], u7 = pr[7];
        const float4 d0 = *(const float4*)&sDx[wv][0];   // broadcast
        const float4 d1 = *(const float4*)&sDx[wv][4];
        float g = fast_tanh(u0)*d0.x + fast_tanh(u1)*d0.y
                + fast_tanh(u2)*d0.z + fast_tanh(u3)*d0.w
                + fast_tanh(u4)*d1.x + fast_tanh(u5)*d1.y
                + fast_tanh(u6)*d1.z + fast_tanh(u7)*d1.w;
        if (s == 0)      kacc = g;
        else if (s == 3) kacc += g;
        else             kacc += 2.0f * g;
        float zs;
        if (s == 3) {
          z0 = z0 + dti * (1.0f/6.0f) * kacc;
          zs = z0;
        } else {
          zs = z0 + ((s == 2) ? dti : 0.5f * dti) * g;
        }
        sZs[wv][l] = zs;
        p2[wv][l] = b2x;  p2[wv][l + 64] = b2y;
      }
      __syncthreads();
    } // stages
  }   // steps

  // ---- readout: logits = zT @ W_read + b_read ; loss + accuracy ----
  if (t < MROWS * OO) {
    const int r = t / OO, o = t % OO;
    float a = b_read[o];
#pragma unroll 8
    for (int k = 0; k < HD; ++k) a = fmaf(sZs[r][k], W_read[k*OO + o], a);
    sLog[r][o] = a;
  }
  __syncthreads();
  if (t < 64) {
    float lv = 0.f, cv = 0.f;
    if (t < MROWS) {
      const int r = t;
      float mx = sLog[r][0]; int am = 0;
#pragma unroll
      for (int o = 1; o < OO; ++o) { const float v = sLog[r][o]; if (v > mx) { mx = v; am = o; } }
      float se = 0.f;
#pragma unroll
      for (int o = 0; o < OO; ++o) se += expf(sLog[r][o] - mx);
      const float lse = mx + logf(se);
      const int yr = yy[row0 + r];
      lv = (lse - sLog[r][yr]) * (1.0f / (float)BB);
      cv = (am == yr) ? 1.0f : 0.0f;
    }
    lv += __shfl_xor(lv, 1); lv += __shfl_xor(lv, 2); lv += __shfl_xor(lv, 4);
    cv += __shfl_xor(cv, 1); cv += __shfl_xor(cv, 2); cv += __shfl_xor(cv, 4);
    if (t == 0) { atomicAdd(&out[0], lv); atomicAdd(&out[1], cv); }
  }
}

extern "C" void kernel_launch(void* const* d_in, const int* in_sizes, int n_in,
                              void* d_out, int out_size, void* d_ws, size_t ws_size,
                              hipStream_t stream) {
  const float* coeffs = (const float*)d_in[0];
  const int*   y      = (const int*)  d_in[1];
  const float* times  = (const float*)d_in[2];
  const float* W_init = (const float*)d_in[3];
  const float* b_init = (const float*)d_in[4];
  const float* W_in   = (const float*)d_in[5];
  const float* b_in   = (const float*)d_in[6];
  const float* W_h    = (const float*)d_in[7];
  const float* b_h    = (const float*)d_in[8];
  const float* W_out  = (const float*)d_in[9];
  const float* b_out  = (const float*)d_in[10];
  const float* W_read = (const float*)d_in[11];
  const float* b_read = (const float*)d_in[12];
  float* out = (float*)d_out;

  zero_out_k<<<1, 64, 0, stream>>>(out);   // d_out is poisoned 0xAA before every replay
  cde_main<<<BB/MROWS, NTHR, 0, stream>>>(coeffs, y, times, W_init, b_init,
                                          W_in, b_in, W_h, b_h, W_out, b_out,
                                          W_read, b_read, out);
}

// Round 4
// 22146.625 us; speedup vs baseline: 1.1341x; 1.0154x over previous
//
#include <hip/hip_runtime.h>

// Problem constants (from reference)
#define BB    2048
#define TT    100
#define CC    8
#define HD    64
#define HHD   128
#define OO    10
#define MROWS 8      // batch rows per block; grid = 256 blocks = 1 block/CU
#define NTHR  512    // 8 waves/block = 2 waves/SIMD; launch_bounds(512,2) -> 256 VGPR cap
// R1: weight refetch penalty at 2 blocks/CU (FETCH 1.2e7->3.1e7) — reverted.
// R3: register-cached weights killed FETCH (1.2e7->5e3 KB warm) but dur flat:
//     VALU-busy TIME identical across R0/R1/R3 (~3.76ms) -> all stall, and the
//     shared resource is the per-CU LDS pipe: ~240 LDS instrs/wave/substage,
//     mostly WAVE-UNIFORM broadcast reads (16B delivered per ~12cy instr) plus
//     8-way same-address ds_atomic serialization (lockstep waves).
// R4 (this): packed per-lane LDS loads (1 instr loads the whole slice into the
//     wave) + v_readlane broadcast (VALU pipe, NOT ds_bpermute) + wave-staggered
//     atomic row order (no same-address collisions in lockstep).

__device__ __forceinline__ float fast_tanh(float x) {
  float e = __expf(2.0f * x);
  return 1.0f - 2.0f / (e + 1.0f);
}

// guaranteed v_readlane_b32 (VALU pipe). lane may be SGPR-uniform or immediate.
__device__ __forceinline__ float rlane(float v, int lane) {
  return __int_as_float(__builtin_amdgcn_readlane(__float_as_int(v), lane));
}

__global__ void zero_out_k(float* o) {
  if (threadIdx.x < 2) o[threadIdx.x] = 0.0f;
}

__global__ void __launch_bounds__(NTHR, 2)
cde_main(const float* __restrict__ coeffs, const int* __restrict__ yy,
         const float* __restrict__ times,
         const float* __restrict__ W_init, const float* __restrict__ b_init,
         const float* __restrict__ W_in,  const float* __restrict__ b_in,
         const float* __restrict__ W_h,   const float* __restrict__ b_h,
         const float* __restrict__ W_out, const float* __restrict__ b_out,
         const float* __restrict__ W_read,const float* __restrict__ b_read,
         float* __restrict__ out)
{
  __shared__ float sZs[MROWS][HD];        // 2KB   stage-input z
  __shared__ float pA [MROWS][HHD];       // 4KB   bias-primed partials, layer A
  __shared__ float p1 [MROWS][HHD];       // 4KB   hidden1
  __shared__ float p2 [MROWS][HHD];       // 4KB   hidden2
  __shared__ float pB [MROWS][576];       // 18KB  big layer, addr = col + (col>>3)
  __shared__ float sDx[MROWS][CC];
  __shared__ float sLog[MROWS][OO];

  const int t    = threadIdx.x;
  const int wv   = t >> 6;        // wave id 0..7
  const int l    = t & 63;        // lane
  const int row0 = blockIdx.x * MROWS;
  // P4 mapping: k-slice q = wv&3 (32k), col-half = wv>>2 (256 cols, 4/lane)
  const int q    = wv & 3;
  const int colb = 256 * (wv >> 2) + 4 * l;
  // packed-load mapping: lane l carries (row = l>>3, k-group = l&7)
  const int prow = l >> 3;
  const int pcol = l & 7;

  // ---- persistent register-cached weights (loaded ONCE) ----
  // W_h layers: wave wv owns k-rows [16wv,16wv+16), cols l and l+64. 64 regs.
  float w1x[16], w1y[16], w2x[16], w2y[16];
#pragma unroll
  for (int j = 0; j < 16; ++j) {
    const float* wr  = W_h + (16*wv + j) * HHD;           // 256B coalesced
    const float* wr2 = wr + HHD*HHD;
    w1x[j] = wr[l];   w1y[j] = wr[l + 64];
    w2x[j] = wr2[l];  w2y[j] = wr2[l + 64];
  }
  // W_out: thread owns rows 32q+4kc+j, cols colb..colb+3. 128 regs.
  float4 wout[8][4];
#pragma unroll
  for (int kc = 0; kc < 8; ++kc)
#pragma unroll
    for (int j = 0; j < 4; ++j)
      wout[kc][j] = *(const float4*)(W_out + (size_t)(32*q + 4*kc + j)*(HD*CC) + colb);

  // biases (7 regs)
  const float binx = b_in[l],      biny = b_in[l + 64];
  const float b1x  = b_h[l],       b1y  = b_h[l + 64];
  const float b2x  = b_h[HHD + l], b2y  = b_h[HHD + l + 64];
  const float boutv = b_out[t];

  // ---- z0 ; thread owns (row wv, h=l) for RK state ----
  float z0, kacc = 0.f;
  {
    const float* cf = coeffs + (size_t)(row0 + wv) * (TT*CC);
    float a = b_init[l];
#pragma unroll
    for (int c = 0; c < CC; ++c) a = fmaf(cf[c], W_init[c*HD + l], a);
    z0 = a;
    sZs[wv][l] = a;
  }

  // ---- prime partial buffers with bias ----
  pA[wv][l] = binx;  pA[wv][l + 64] = biny;
  p1[wv][l] = b1x;   p1[wv][l + 64] = b1y;
  p2[wv][l] = b2x;   p2[wv][l + 64] = b2y;
#pragma unroll
  for (int r = 0; r < MROWS; ++r) pB[r][t + (t >> 3)] = boutv;
  __syncthreads();

#pragma unroll 1
  for (int step = 0; step < TT-1; ++step) {
    const float dti = times[step+1] - times[step];
    if (t < 64) {   // sDx readers (P5) are barrier-separated both directions
      const int r = t >> 3, c = t & 7;
      const float* cf = coeffs + (size_t)(row0 + r)*(TT*CC) + step*CC + c;
      sDx[r][c] = (cf[CC] - cf[0]) / dti;
    }

#pragma unroll 1
    for (int s = 0; s < 4; ++s) {
      // ---- P1: layer A. k in [8wv,8wv+8). one packed ds_read_b32 gives the
      //      wave all 64 z-values; broadcast via readlane. + prime pB ----
      {
        float wx[8], wy[8];
#pragma unroll
        for (int j = 0; j < 8; ++j) {
          const float* wr = W_in + (8*wv + j) * HHD;      // L2-hot stream
          wx[j] = wr[l];
          wy[j] = wr[l + 64];
        }
        const float zp = sZs[prow][8*wv + pcol];          // packed per-lane
#pragma unroll
        for (int i = 0; i < MROWS; ++i) {
          const int rr = (i + wv) & 7;                    // staggered rows
          float a0 = 0.f, a1 = 0.f;
#pragma unroll
          for (int kk = 0; kk < 8; ++kk) {
            const float sv = rlane(zp, rr*8 + kk);
            a0 = fmaf(sv, wx[kk], a0);
            a1 = fmaf(sv, wy[kk], a1);
          }
          atomicAdd(&pA[rr][l],      a0);
          atomicAdd(&pA[rr][l + 64], a1);
        }
#pragma unroll
        for (int r = 0; r < MROWS; ++r) pB[r][t + (t >> 3)] = boutv;
      }
      __syncthreads();
      // ---- P2: hidden1. one packed b64 -> relu -> readlane broadcast ----
      {
        const float2 pk = *(const float2*)&pA[prow][16*wv + 2*pcol];
        const float r0 = fmaxf(pk.x, 0.f), r1 = fmaxf(pk.y, 0.f);
#pragma unroll
        for (int i = 0; i < MROWS; ++i) {
          const int rr = (i + wv) & 7;
          float a0 = 0.f, a1 = 0.f;
#pragma unroll
          for (int kk = 0; kk < 16; ++kk) {
            const float sv = rlane((kk & 1) ? r1 : r0, rr*8 + (kk >> 1));
            a0 = fmaf(sv, w1x[kk], a0);
            a1 = fmaf(sv, w1y[kk], a1);
          }
          atomicAdd(&p1[rr][l],      a0);
          atomicAdd(&p1[rr][l + 64], a1);
        }
      }
      __syncthreads();
      // ---- P3: hidden2, same scheme + rebias pA ----
      {
        const float2 pk = *(const float2*)&p1[prow][16*wv + 2*pcol];
        const float r0 = fmaxf(pk.x, 0.f), r1 = fmaxf(pk.y, 0.f);
#pragma unroll
        for (int i = 0; i < MROWS; ++i) {
          const int rr = (i + wv) & 7;
          float a0 = 0.f, a1 = 0.f;
#pragma unroll
          for (int kk = 0; kk < 16; ++kk) {
            const float sv = rlane((kk & 1) ? r1 : r0, rr*8 + (kk >> 1));
            a0 = fmaf(sv, w2x[kk], a0);
            a1 = fmaf(sv, w2y[kk], a1);
          }
          atomicAdd(&p2[rr][l],      a0);
          atomicAdd(&p2[rr][l + 64], a1);
        }
        pA[wv][l] = binx;  pA[wv][l + 64] = biny;
      }
      __syncthreads();
      // ---- P4: big layer, register W_out. one packed b128 -> relu ->
      //      readlane broadcast. k in [32q,32q+32), cols colb..+3. ----
      {
        const float4 pv = *(const float4*)&p2[prow][32*q + 4*pcol];
        const float p4k[4] = { fmaxf(pv.x,0.f), fmaxf(pv.y,0.f),
                               fmaxf(pv.z,0.f), fmaxf(pv.w,0.f) };
#pragma unroll
        for (int i = 0; i < MROWS; ++i) {
          const int r = (i + wv) & 7;                     // stagger: q-groups
          float ac0=0.f, ac1=0.f, ac2=0.f, ac3=0.f;       // 0..3 / 4..7 disjoint
#pragma unroll
          for (int kc = 0; kc < 8; ++kc) {
#pragma unroll
            for (int j = 0; j < 4; ++j) {
              const float sv = rlane(p4k[j], r*8 + kc);
              ac0 = fmaf(sv, wout[kc][j].x, ac0);
              ac1 = fmaf(sv, wout[kc][j].y, ac1);
              ac2 = fmaf(sv, wout[kc][j].z, ac2);
              ac3 = fmaf(sv, wout[kc][j].w, ac3);
            }
          }
          atomicAdd(&pB[r][(colb    ) + ((colb    ) >> 3)], ac0);
          atomicAdd(&pB[r][(colb + 1) + ((colb + 1) >> 3)], ac1);
          atomicAdd(&pB[r][(colb + 2) + ((colb + 2) >> 3)], ac2);
          atomicAdd(&pB[r][(colb + 3) + ((colb + 3) >> 3)], ac3);
        }
        p1[wv][l] = b1x;  p1[wv][l + 64] = b1y;
      }
      __syncthreads();
      // ---- P5: epilogue (tanh, einsum dX, RK) + rebias p2 ----
      {
        const float* pr = &pB[wv][9*l];       // cols 8l..8l+7, stride-9 conflict-free
        const float u0 = pr[0], u1 = pr[1], u2 = pr[2], u3 = pr[3];
        const float u4 = pr[4], u5 = pr[5], u6 = pr[6], u7 = pr[7];
        const float4 d0 = *(const float4*)&sDx[wv][0];   // broadcast
        const float4 d1 = *(const float4*)&sDx[wv][4];
        float g = fast_tanh(u0)*d0.x + fast_tanh(u1)*d0.y
                + fast_tanh(u2)*d0.z + fast_tanh(u3)*d0.w
                + fast_tanh(u4)*d1.x + fast_tanh(u5)*d1.y
                + fast_tanh(u6)*d1.z + fast_tanh(u7)*d1.w;
        if (s == 0)      kacc = g;
        else if (s == 3) kacc += g;
        else             kacc += 2.0f * g;
        float zs;
        if (s == 3) {
          z0 = z0 + dti * (1.0f/6.0f) * kacc;
          zs = z0;
        } else {
          zs = z0 + ((s == 2) ? dti : 0.5f * dti) * g;
        }
        sZs[wv][l] = zs;
        p2[wv][l] = b2x;  p2[wv][l + 64] = b2y;
      }
      __syncthreads();
    } // stages
  }   // steps

  // ---- readout: logits = zT @ W_read + b_read ; loss + accuracy ----
  if (t < MROWS * OO) {
    const int r = t / OO, o = t % OO;
    float a = b_read[o];
#pragma unroll 8
    for (int k = 0; k < HD; ++k) a = fmaf(sZs[r][k], W_read[k*OO + o], a);
    sLog[r][o] = a;
  }
  __syncthreads();
  if (t < 64) {
    float lv = 0.f, cv = 0.f;
    if (t < MROWS) {
      const int r = t;
      float mx = sLog[r][0]; int am = 0;
#pragma unroll
      for (int o = 1; o < OO; ++o) { const float v = sLog[r][o]; if (v > mx) { mx = v; am = o; } }
      float se = 0.f;
#pragma unroll
      for (int o = 0; o < OO; ++o) se += expf(sLog[r][o] - mx);
      const float lse = mx + logf(se);
      const int yr = yy[row0 + r];
      lv = (lse - sLog[r][yr]) * (1.0f / (float)BB);
      cv = (am == yr) ? 1.0f : 0.0f;
    }
    lv += __shfl_xor(lv, 1); lv += __shfl_xor(lv, 2); lv += __shfl_xor(lv, 4);
    cv += __shfl_xor(cv, 1); cv += __shfl_xor(cv, 2); cv += __shfl_xor(cv, 4);
    if (t == 0) { atomicAdd(&out[0], lv); atomicAdd(&out[1], cv); }
  }
}

extern "C" void kernel_launch(void* const* d_in, const int* in_sizes, int n_in,
                              void* d_out, int out_size, void* d_ws, size_t ws_size,
                              hipStream_t stream) {
  const float* coeffs = (const float*)d_in[0];
  const int*   y      = (const int*)  d_in[1];
  const float* times  = (const float*)d_in[2];
  const float* W_init = (const float*)d_in[3];
  const float* b_init = (const float*)d_in[4];
  const float* W_in   = (const float*)d_in[5];
  const float* b_in   = (const float*)d_in[6];
  const float* W_h    = (const float*)d_in[7];
  const float* b_h    = (const float*)d_in[8];
  const float* W_out  = (const float*)d_in[9];
  const float* b_out  = (const float*)d_in[10];
  const float* W_read = (const float*)d_in[11];
  const float* b_read = (const float*)d_in[12];
  float* out = (float*)d_out;

  zero_out_k<<<1, 64, 0, stream>>>(out);   // d_out is poisoned 0xAA before every replay
  cde_main<<<BB/MROWS, NTHR, 0, stream>>>(coeffs, y, times, W_init, b_init,
                                          W_in, b_in, W_h, b_h, W_out, b_out,
                                          W_read, b_read, out);
}